// Round 3
// baseline (3992.862 us; speedup 1.0000x reference)
//
#include <hip/hip_runtime.h>
#include <hip/hip_bf16.h>
#include <math.h>

typedef __attribute__((ext_vector_type(8))) short bf16x8;
typedef __attribute__((ext_vector_type(4))) float f32x4;

#define EPI_T   0  // out bf16 = gelu(acc+b)
#define EPI_H0  1  // out fp32 h = acc+b ; ob2 = bf16(h)
#define EPI_K1  2  // k1=gelu; write k1b; hu = h + dt/8*k1; ob2 = bf16(h + dt/3*k1)
#define EPI_K2  3  // k2=gelu; write k2b; hu += 3dt/8*k2; ob2 = bf16(h - dt/3*k1 + dt*k2)
#define EPI_K3  4  // k3=gelu; hu += 3dt/8*k3; ob2 = bf16(h + dt*(k1-k2+k3))
#define EPI_K4  5  // k4=gelu; h = hu + dt/8*k4 (fp32 out); ob2 = bf16(h)
#define EPI_OUT 6  // out fp32 = acc+b

static __device__ __forceinline__ unsigned short f2bf(float f) {
  unsigned int u = __float_as_uint(f);
  u += 0x7FFFu + ((u >> 16) & 1u);   // RNE
  return (unsigned short)(u >> 16);
}
static __device__ __forceinline__ float bf2f(unsigned short s) {
  return __uint_as_float(((unsigned int)s) << 16);
}
static __device__ __forceinline__ float gelu_f(float x) {
  return 0.5f * x * (1.0f + erff(x * 0.70710678118654752f));
}

typedef __attribute__((address_space(3))) unsigned int lds_u32;
typedef const __attribute__((address_space(1))) unsigned int glb_u32;
static __device__ __forceinline__ void gl_lds16(const unsigned short* g, unsigned short* l) {
  __builtin_amdgcn_global_load_lds((glb_u32*)g, (lds_u32*)l, 16, 0, 0);
}

// C[M,N] = epi(A[M,K](bf16) @ Wt[N,K]^T + bias).
// BM=64 BN=64 BK=64, 4 waves (2M x 2N, 32x32 each). grid = 32*(N/64) blocks
// -> 2 blocks/CU (2 waves/SIMD) for latency hiding; barriers decoupled across blocks.
// A staged via swizzled global_load_lds; B (weights) direct global->VGPR (L1/L2-hit).
template<int EPI>
__global__ __launch_bounds__(256)
void gemm_k(const unsigned short* __restrict__ A,
            const unsigned short* __restrict__ Wt,
            const float* __restrict__ bias,
            void* __restrict__ outp,
            unsigned short* __restrict__ ob2,
            const float* __restrict__ hF,
            float* __restrict__ huF,
            const unsigned short* __restrict__ k1p,
            const unsigned short* __restrict__ k2p,
            float dt, int N, int K, int nwg)
{
  __shared__ __attribute__((aligned(16))) unsigned short As[2][64][64];

  // bijective XCD swizzle (all nwg here are multiples of 8)
  const int bid = blockIdx.x;
  const int cpx = nwg >> 3;
  const int wid = (bid & 7) * cpx + (bid >> 3);
  const int nbx = N >> 6;
  const int bx = wid % nbx, by = wid / nbx;
  const int brow = by << 6, bcol = bx << 6;

  const int tid = threadIdx.x;
  const int lane = tid & 63;
  const int wv = tid >> 6;
  const int wr = wv >> 1, wc = wv & 1;       // wave -> 32x32 sub-tile
  const int l15 = lane & 15, l4 = lane >> 4;
  const int lr = lane >> 3;                  // row within 8-row staging group
  const int sc = (lane & 7) ^ lr;            // inverse-swizzled source chunk
  const int KT = K >> 6;

  f32x4 acc[2][2];
  const f32x4 zf = {0.f, 0.f, 0.f, 0.f};
#pragma unroll
  for (int m = 0; m < 2; ++m)
#pragma unroll
    for (int n = 0; n < 2; ++n) acc[m][n] = zf;

  // per-lane B fragment base pointers (col = bcol + wc*32 + n*16 + l15)
  const unsigned short* pB0 = Wt + (size_t)(bcol + wc * 32 + l15) * K + l4 * 8;
  const unsigned short* pB1 = pB0 + (size_t)16 * K;

  // LDS(row, c) holds global chunk c ^ (row&7); dest linear, source pre-swizzled.
  auto STAGE = [&](int buf, int kt) {
    const int kof = kt << 6;  // shorts
#pragma unroll
    for (int c = 0; c < 2; ++c) {
      const int r0 = c * 32 + wv * 8;
      gl_lds16(A + (size_t)(brow + r0 + lr) * K + kof + sc * 8, &As[buf][r0][0]);
    }
  };

  STAGE(0, 0);
  int b = 0;
  for (int kt = 0; kt < KT; ++kt) {
    __syncthreads();                       // drains vmcnt -> buf b ready; guards buf b^1 reuse
    if (kt + 1 < KT) STAGE(b ^ 1, kt + 1); // prefetch next A tile (completes under compute)
    // B fragments for this K-tile, direct from global (L1/L2-resident weights)
    bf16x8 bg0[2], bg1[2];
#pragma unroll
    for (int ks = 0; ks < 2; ++ks) {
      bg0[ks] = *(const bf16x8*)(pB0 + kt * 64 + ks * 32);
      bg1[ks] = *(const bf16x8*)(pB1 + kt * 64 + ks * 32);
    }
#pragma unroll
    for (int ks = 0; ks < 2; ++ks) {
      const int ch = ((ks * 4 + l4) ^ (l15 & 7)) * 8;   // swizzled read chunk
      bf16x8 af0 = *(const bf16x8*)&As[b][wr * 32 + l15][ch];
      bf16x8 af1 = *(const bf16x8*)&As[b][wr * 32 + 16 + l15][ch];
      acc[0][0] = __builtin_amdgcn_mfma_f32_16x16x32_bf16(af0, bg0[ks], acc[0][0], 0, 0, 0);
      acc[0][1] = __builtin_amdgcn_mfma_f32_16x16x32_bf16(af0, bg1[ks], acc[0][1], 0, 0, 0);
      acc[1][0] = __builtin_amdgcn_mfma_f32_16x16x32_bf16(af1, bg0[ks], acc[1][0], 0, 0, 0);
      acc[1][1] = __builtin_amdgcn_mfma_f32_16x16x32_bf16(af1, bg1[ks], acc[1][1], 0, 0, 0);
    }
    b ^= 1;
  }

  const float dt3 = dt * (1.f / 3.f), dt8 = dt * 0.125f, dt38 = dt * 0.375f;
#pragma unroll
  for (int n = 0; n < 2; ++n) {
    const int col = bcol + wc * 32 + n * 16 + l15;
    const float bv = bias[col];
#pragma unroll
    for (int m = 0; m < 2; ++m) {
      const int r0 = brow + wr * 32 + m * 16 + l4 * 4;
#pragma unroll
      for (int r = 0; r < 4; ++r) {
        const int row = r0 + r;
        const float a = acc[m][n][r] + bv;
        const size_t ix = (size_t)row * N + col;     // out index
        const size_t ih = (size_t)row * 1024 + col;  // aux index (N==1024 EPIs only)
        if constexpr (EPI == EPI_T) {
          ((unsigned short*)outp)[ix] = f2bf(gelu_f(a));
        } else if constexpr (EPI == EPI_H0) {
          ((float*)outp)[ix] = a;
          ob2[ix] = f2bf(a);
        } else if constexpr (EPI == EPI_K1) {
          const float k1 = gelu_f(a);
          const float h = hF[ih];
          ((unsigned short*)outp)[ih] = f2bf(k1);
          huF[ih] = h + dt8 * k1;
          ob2[ih] = f2bf(h + dt3 * k1);
        } else if constexpr (EPI == EPI_K2) {
          const float k2 = gelu_f(a);
          const float h = hF[ih];
          const float k1 = bf2f(k1p[ih]);
          ((unsigned short*)outp)[ih] = f2bf(k2);
          huF[ih] += dt38 * k2;
          ob2[ih] = f2bf(h - dt3 * k1 + dt * k2);
        } else if constexpr (EPI == EPI_K3) {
          const float k3 = gelu_f(a);
          const float h = hF[ih];
          const float k1 = bf2f(k1p[ih]);
          const float k2 = bf2f(k2p[ih]);
          huF[ih] += dt38 * k3;
          ob2[ih] = f2bf(h + dt * (k1 - k2 + k3));
        } else if constexpr (EPI == EPI_K4) {
          const float k4 = gelu_f(a);
          const float hn = huF[ih] + dt8 * k4;
          ((float*)outp)[ih] = hn;
          ob2[ih] = f2bf(hn);
        } else {  // EPI_OUT
          ((float*)outp)[ix] = a;
        }
      }
    }
  }
}

// W [K][N] fp32 -> Wt [N][K] bf16
__global__ void transpose_k(const float* __restrict__ W, unsigned short* __restrict__ Wt,
                            int K, int N) {
  __shared__ float tile[32][33];
  const int n0 = blockIdx.x * 32, k0 = blockIdx.y * 32;
  const int lx = threadIdx.x, ly = threadIdx.y;
#pragma unroll
  for (int r = ly; r < 32; r += 8)
    tile[r][lx] = W[(size_t)(k0 + r) * N + n0 + lx];
  __syncthreads();
#pragma unroll
  for (int r = ly; r < 32; r += 8)
    Wt[(size_t)(n0 + r) * K + k0 + lx] = f2bf(tile[lx][r]);
}

// x[:,0,:] fp32 [2048][16][512] -> xb bf16 [2048][512]
__global__ void convx_k(const float* __restrict__ x, unsigned short* __restrict__ xb) {
  const int r = blockIdx.x;
  const int c = threadIdx.x << 3;
  const float* s = x + (size_t)r * 8192 + c;
  f32x4 u0 = *(const f32x4*)s;
  f32x4 u1 = *(const f32x4*)(s + 4);
  union { unsigned short q[8]; bf16x8 v; } t;
#pragma unroll
  for (int j = 0; j < 4; ++j) { t.q[j] = f2bf(u0[j]); t.q[4 + j] = f2bf(u1[j]); }
  *(bf16x8*)(xb + (size_t)r * 512 + c) = t.v;
}

template<int EPI>
static inline void G(hipStream_t st, const void* A, const unsigned short* Wt,
                     const float* bias, void* out, void* ob2,
                     const float* hF, float* huF,
                     const unsigned short* k1p, const unsigned short* k2p,
                     float dt, int N, int K) {
  const int nwg = (2048 / 64) * (N / 64);
  gemm_k<EPI><<<nwg, 256, 0, st>>>((const unsigned short*)A, Wt, bias, out,
                                   (unsigned short*)ob2, hF, huF, k1p, k2p, dt, N, K, nwg);
}

extern "C" void kernel_launch(void* const* d_in, const int* in_sizes, int n_in,
                              void* d_out, int out_size, void* d_ws, size_t ws_size,
                              hipStream_t stream) {
  const float* x   = (const float*)d_in[0];
  const float* Wi  = (const float*)d_in[1];
  const float* bi  = (const float*)d_in[2];
  const float* W1  = (const float*)d_in[3];
  const float* b1  = (const float*)d_in[4];
  const float* W2  = (const float*)d_in[5];
  const float* b2  = (const float*)d_in[6];
  const float* W3  = (const float*)d_in[7];
  const float* b3  = (const float*)d_in[8];
  const float* Wo1 = (const float*)d_in[9];
  const float* bo1 = (const float*)d_in[10];
  const float* Wo2 = (const float*)d_in[11];
  const float* bo2 = (const float*)d_in[12];

  char* ws = (char*)d_ws;
  unsigned short* Wti  = (unsigned short*)(ws + (0ull  << 20));  // [1024][512]
  unsigned short* Wt1  = (unsigned short*)(ws + (1ull  << 20));  // [1024][1024]
  unsigned short* Wt2  = (unsigned short*)(ws + (3ull  << 20));
  unsigned short* Wt3  = (unsigned short*)(ws + (5ull  << 20));
  unsigned short* Wto1 = (unsigned short*)(ws + (7ull  << 20));  // [512][1024]
  unsigned short* Wto2 = (unsigned short*)(ws + (8ull  << 20));  // [64][512]
  float*          h    = (float*)(ws + (9ull  << 20));           // fp32 [2048][1024]
  float*          hu   = (float*)(ws + (17ull << 20));           // fp32 [2048][1024]
  unsigned short* xb   = (unsigned short*)hu;                    // alias: xb dead before hu live
  unsigned short* k1b  = (unsigned short*)(ws + (25ull << 20));  // bf16 [2048][1024]
  unsigned short* o1b  = k1b;                                    // alias: k1b dead before o1b live
  unsigned short* k2b  = (unsigned short*)(ws + (29ull << 20));
  unsigned short* t1b  = (unsigned short*)(ws + (33ull << 20));
  unsigned short* t2b  = (unsigned short*)(ws + (37ull << 20));
  unsigned short* cA   = (unsigned short*)(ws + (41ull << 20));  // combo A input
  unsigned short* hb   = (unsigned short*)(ws + (45ull << 20));  // bf16(h)

  dim3 tb(32, 8);
  transpose_k<<<dim3(1024 / 32,  512 / 32), tb, 0, stream>>>(Wi,  Wti,  512, 1024);
  transpose_k<<<dim3(1024 / 32, 1024 / 32), tb, 0, stream>>>(W1,  Wt1, 1024, 1024);
  transpose_k<<<dim3(1024 / 32, 1024 / 32), tb, 0, stream>>>(W2,  Wt2, 1024, 1024);
  transpose_k<<<dim3(1024 / 32, 1024 / 32), tb, 0, stream>>>(W3,  Wt3, 1024, 1024);
  transpose_k<<<dim3( 512 / 32, 1024 / 32), tb, 0, stream>>>(Wo1, Wto1, 1024, 512);
  transpose_k<<<dim3(  64 / 32,  512 / 32), tb, 0, stream>>>(Wo2, Wto2,  512,  64);
  convx_k<<<2048, 64, 0, stream>>>(x, xb);

  const float dt = 1.0f / 15.0f;

  // h0 = x0 @ Wi + bi  (fp32 h + bf16 hb)
  G<EPI_H0>(stream, xb, Wti, bi, h, hb, nullptr, nullptr, nullptr, nullptr, dt, 1024, 512);

  for (int s = 0; s < 15; ++s) {
    // k1 = f(h)
    G<EPI_T >(stream, hb,  Wt1, b1, t1b, nullptr, nullptr, nullptr, nullptr, nullptr, dt, 1024, 1024);
    G<EPI_T >(stream, t1b, Wt2, b2, t2b, nullptr, nullptr, nullptr, nullptr, nullptr, dt, 1024, 1024);
    G<EPI_K1>(stream, t2b, Wt3, b3, k1b, cA, h, hu, nullptr, nullptr, dt, 1024, 1024);
    // k2 = f(h + dt/3 k1)
    G<EPI_T >(stream, cA,  Wt1, b1, t1b, nullptr, nullptr, nullptr, nullptr, nullptr, dt, 1024, 1024);
    G<EPI_T >(stream, t1b, Wt2, b2, t2b, nullptr, nullptr, nullptr, nullptr, nullptr, dt, 1024, 1024);
    G<EPI_K2>(stream, t2b, Wt3, b3, k2b, cA, h, hu, k1b, nullptr, dt, 1024, 1024);
    // k3 = f(h - dt/3 k1 + dt k2)
    G<EPI_T >(stream, cA,  Wt1, b1, t1b, nullptr, nullptr, nullptr, nullptr, nullptr, dt, 1024, 1024);
    G<EPI_T >(stream, t1b, Wt2, b2, t2b, nullptr, nullptr, nullptr, nullptr, nullptr, dt, 1024, 1024);
    G<EPI_K3>(stream, t2b, Wt3, b3, nullptr, cA, h, hu, k1b, k2b, dt, 1024, 1024);
    // k4 = f(h + dt(k1-k2+k3)) ; h = hu + dt/8 k4
    G<EPI_T >(stream, cA,  Wt1, b1, t1b, nullptr, nullptr, nullptr, nullptr, nullptr, dt, 1024, 1024);
    G<EPI_T >(stream, t1b, Wt2, b2, t2b, nullptr, nullptr, nullptr, nullptr, nullptr, dt, 1024, 1024);
    G<EPI_K4>(stream, t2b, Wt3, b3, h, hb, nullptr, hu, nullptr, nullptr, dt, 1024, 1024);
  }

  // out = gelu(h @ Wo1 + bo1) @ Wo2 + bo2
  G<EPI_T  >(stream, hb,  Wto1, bo1, o1b, nullptr, nullptr, nullptr, nullptr, nullptr, dt, 512, 1024);
  G<EPI_OUT>(stream, o1b, Wto2, bo2, d_out, nullptr, nullptr, nullptr, nullptr, nullptr, dt, 64, 512);
}